// Round 5
// baseline (2100.600 us; speedup 1.0000x reference)
//
#include <hip/hip_runtime.h>
#include <stdint.h>

// VectorQuantizer (eval fwd): inputs [64,64,32,32] f32 NCHW, embedding [1024,64] f32.
// Outputs: quantized [4194304] f32, loss, perplexity.
//
// MFMA distance pass (f16 hi/lo 3-term split) + PROVABLE safety nets:
//  - gap-flag 0.5 (approx-error bound ~0.06 incl. denorm flush -> 8x margin)
//  - per-row value audit: exact fp32 dist(selected) must match MFMA best1 (+-0.05)
//    -> catches any label-permutation or per-row value corruption
//  - packed-table self-check -> forces full exact fallback if tables corrupt
//  - flagged rows re-resolved by the round-3-proven exact fp32 path.

#define K_CODES 1024
#define DIM 64
#define HW 1024
#define N_ROWS 65536
#define OUT_ELEMS 4194304
#define GAPF 0.5f
#define TOLF 0.05f

// ws float-slot offsets
#define WS_E2F   0        // 1024 f32 ||e||^2
#define WS_CNT   1024     // 1024 u32 counts
#define WS_LOSS  2048     // f32
#define WS_NFLAG 2049     // u32
#define WS_TBAD  2050     // u32 table-corrupt flag
#define WS_E2PK  2176     // 1024 u32 (f16 pair e2hi|e2lo)
#define WS_EHI   3200     // u16[65536] frag-major f16 of -2e
#define WS_ELO   19584    // u16[65536]
#define WS_IDXF  35968    // u16[65536]: bits0-9 code, bit15 gap-flag
#define WS_BD1   68736    // f32[65536]: MFMA best1 per row
#define WS_FLGF  134272   // u16[65536]: flagged row list
#define WS_NEED_FLOATS 167040

typedef _Float16 f16x8 __attribute__((ext_vector_type(8)));
typedef float    f32x4 __attribute__((ext_vector_type(4)));

union U4 { uint32_t u[4]; f16x8 f; };
union PK { _Float16 h[2]; uint32_t u; };

__device__ __forceinline__ int frag_off(int k, int d) {
    const int ct = k >> 4, m = k & 15;
    const int s_ = d >> 5, kc = (d >> 3) & 3, j = d & 7;
    return (((ct*2 + s_) * 64) + kc*16 + m) * 8 + j;
}

// ---------------- prep: e2, f16 splits in MFMA-fragment-major layout ----------------
__global__ void vq_prep(const float* __restrict__ emb, float* __restrict__ ws) {
    const int k = blockIdx.x * 256 + threadIdx.x;  // grid 4 x 256
    if (k == 0) {
        ws[WS_LOSS] = 0.f;
        reinterpret_cast<uint32_t*>(ws)[WS_NFLAG] = 0u;
        reinterpret_cast<uint32_t*>(ws)[WS_TBAD]  = 0u;
    }
    if (k >= K_CODES) return;
    const float4* e4 = reinterpret_cast<const float4*>(emb + k * DIM);
    float s = 0.f;
#pragma unroll
    for (int i = 0; i < 16; ++i) {
        float4 v = e4[i];
        s += v.x*v.x + v.y*v.y + v.z*v.z + v.w*v.w;
    }
    ws[WS_E2F + k] = s;
    reinterpret_cast<uint32_t*>(ws)[WS_CNT + k] = 0u;
    PK pk; pk.h[0] = (_Float16)s; pk.h[1] = (_Float16)(s - (float)pk.h[0]);
    reinterpret_cast<uint32_t*>(ws)[WS_E2PK + k] = pk.u;

    _Float16* ehi = reinterpret_cast<_Float16*>(ws + WS_EHI);
    _Float16* elo = reinterpret_cast<_Float16*>(ws + WS_ELO);
    const float* e = emb + k * DIM;
#pragma unroll
    for (int d = 0; d < 64; ++d) {
        float v = -2.f * e[d];
        _Float16 h = (_Float16)v;
        _Float16 lo = (_Float16)(v - (float)h);
        const int off = frag_off(k, d);
        ehi[off] = h; elo[off] = lo;
    }
}

// ---------------- table self-check: any corruption -> force full exact fallback ----
__global__ void vq_tabcheck(const float* __restrict__ emb, float* __restrict__ ws) {
    const int k = blockIdx.x * 256 + threadIdx.x;  // grid 4 x 256
    if (k >= K_CODES) return;
    const _Float16* ehi = reinterpret_cast<const _Float16*>(ws + WS_EHI);
    const _Float16* elo = reinterpret_cast<const _Float16*>(ws + WS_ELO);
    bool bad = false;
#pragma unroll 8
    for (int d = 0; d < 64; ++d) {
        const float v = -2.f * emb[k * DIM + d];
        const int off = frag_off(k, d);
        const float r = (float)ehi[off] + (float)elo[off];
        if (fabsf(r - v) > 1e-2f + 1e-3f * fabsf(v)) bad = true;
    }
    {   // e2 pair check
        PK pk; pk.u = reinterpret_cast<const uint32_t*>(ws)[WS_E2PK + k];
        const float r = (float)pk.h[0] + (float)pk.h[1];
        const float v = ws[WS_E2F + k];
        if (fabsf(r - v) > 1e-2f + 1e-3f * fabsf(v)) bad = true;
    }
    if (bad) reinterpret_cast<uint32_t*>(ws)[WS_TBAD] = 1u;
}

// ---------------- MFMA argmin: 16x16x32 f16, tile = 16 codes x 16 pixels ----------------
__global__ __launch_bounds__(256) void vq_mfma(const float* __restrict__ in,
                                               float* __restrict__ ws) {
    __shared__ __align__(16) float smemf[8320];   // 33280 B
    char* smem = (char*)smemf;

    const int t = threadIdx.x, blk = blockIdx.x;
    const int wid = t >> 6, l = t & 63;
    const int n = l & 15, kc = l >> 4;
    const int row0 = blk * 64;
    const int b = row0 >> 10, hw0 = row0 & 1023;

    // phase 1: stage x[64 px][64 c] fp32 -> lds [64][68]
    {
        const float* xin = in + b * (DIM*HW) + hw0;
        const int i = t & 63, cg = t >> 6;
#pragma unroll
        for (int cc = 0; cc < 16; ++cc) {
            const int c = cg*16 + cc;
            smemf[i*68 + c] = xin[c*HW + i];
        }
    }
    __syncthreads();

    // phase 2: per-lane B-frags (x hi/lo), loop-invariant over all codes
    f16x8 bh[2], bl[2];
    {
        const int p = wid*16 + n;
#pragma unroll
        for (int s = 0; s < 2; ++s) {
            float v[8];
            const float* base = smemf + p*68 + s*32 + kc*8;
            *(float4*)(v)     = *(const float4*)(base);
            *(float4*)(v + 4) = *(const float4*)(base + 4);
#pragma unroll
            for (int j = 0; j < 8; ++j) {
                _Float16 h = (_Float16)v[j];
                bh[s][j] = h;
                bl[s][j] = (_Float16)(v[j] - (float)h);
            }
        }
    }
    __syncthreads();

    float best1 = 3.4e38f, best2 = 3.4e38f;
    int bestk = 0;
    const uint4*    ehi_g = reinterpret_cast<const uint4*>(ws + WS_EHI);
    const uint4*    elo_g = reinterpret_cast<const uint4*>(ws + WS_ELO);
    const uint32_t* e2_g  = reinterpret_cast<const uint32_t*>(ws) + WS_E2PK;
    uint32_t* e2l = reinterpret_cast<uint32_t*>(smem + 32768);
    const uint32_t be2u = (kc == 0) ? 0x3C003C00u : 0u;   // f16 1.0 pair

    for (int ch = 0; ch < 8; ++ch) {
        uint4 sh[4], sl[4];
#pragma unroll
        for (int r = 0; r < 4; ++r) {
            sh[r] = ehi_g[ch*1024 + r*256 + t];
            sl[r] = elo_g[ch*1024 + r*256 + t];
        }
        const uint32_t e2v = (t < 128) ? e2_g[ch*128 + t] : 0u;
        __syncthreads();   // previous chunk's compute done
#pragma unroll
        for (int r = 0; r < 4; ++r) {
            *(uint4*)(smem +          (r*256 + t)*16) = sh[r];
            *(uint4*)(smem + 16384 + (r*256 + t)*16) = sl[r];
        }
        if (t < 128) e2l[t] = e2v;
        __syncthreads();

        for (int ctl = 0; ctl < 8; ++ctl) {
            const char* hb  = smem +          (ctl*2)*1024 + l*16;
            const char* lb2 = smem + 16384 + (ctl*2)*1024 + l*16;
            f16x8 ah0 = *(const f16x8*)(hb);
            f16x8 ah1 = *(const f16x8*)(hb + 1024);
            f16x8 al0 = *(const f16x8*)(lb2);
            f16x8 al1 = *(const f16x8*)(lb2 + 1024);
            const uint32_t e2p = e2l[ctl*16 + n];
            U4 ae2; ae2.u[0] = (kc == 0) ? e2p : 0u; ae2.u[1] = 0; ae2.u[2] = 0; ae2.u[3] = 0;
            U4 be2; be2.u[0] = be2u;                 be2.u[1] = 0; be2.u[2] = 0; be2.u[3] = 0;
            const f32x4 z = {0.f, 0.f, 0.f, 0.f};
            f32x4 a0 = __builtin_amdgcn_mfma_f32_16x16x32_f16(ah0, bh[0], z, 0, 0, 0);
            a0 = __builtin_amdgcn_mfma_f32_16x16x32_f16(ah1, bh[1], a0, 0, 0, 0);
            a0 = __builtin_amdgcn_mfma_f32_16x16x32_f16(ae2.f, be2.f, a0, 0, 0, 0);
            f32x4 a1 = __builtin_amdgcn_mfma_f32_16x16x32_f16(ah0, bl[0], z, 0, 0, 0);
            a1 = __builtin_amdgcn_mfma_f32_16x16x32_f16(ah1, bl[1], a1, 0, 0, 0);
            a1 = __builtin_amdgcn_mfma_f32_16x16x32_f16(al0, bh[0], a1, 0, 0, 0);
            a1 = __builtin_amdgcn_mfma_f32_16x16x32_f16(al1, bh[1], a1, 0, 0, 0);
            const int cbase = ch*128 + ctl*16 + kc*4;
#pragma unroll
            for (int r = 0; r < 4; ++r) {
                const float d = a0[r] + a1[r];
                const float mx = fmaxf(d, best1);
                best2 = fminf(best2, mx);
                const bool c = d < best1;
                best1 = c ? d : best1;
                bestk = c ? (cbase + r) : bestk;
            }
        }
    }

    // merge across the 4 kc-lanes of each pixel (lex: preserves lowest-k on ties)
#pragma unroll
    for (int off = 16; off <= 32; off <<= 1) {
        const float od  = __shfl_xor(best1, off, 64);
        const int   ok  = __shfl_xor(bestk, off, 64);
        const float ob2 = __shfl_xor(best2, off, 64);
        best2 = fminf(fminf(best2, ob2), fmaxf(best1, od));
        const bool c = (od < best1) || (od == best1 && ok < bestk);
        best1 = c ? od : best1;
        bestk = c ? ok : bestk;
    }
    if (kc == 0) {
        const int row = row0 + wid*16 + n;
        uint16_t tag = (uint16_t)bestk;
        if (best2 - best1 <= GAPF) tag |= 0x8000u;
        reinterpret_cast<uint16_t*>(ws + WS_IDXF)[row] = tag;
        ws[WS_BD1 + row] = best1;
    }
}

// ---------------- per-row value audit; builds the flagged-row list ----------------
__global__ __launch_bounds__(256) void vq_verify(const float* __restrict__ in,
                                                 const float* __restrict__ emb,
                                                 float* __restrict__ ws) {
    const int row = blockIdx.x * 256 + threadIdx.x;  // grid 256 x 256
    const uint16_t tag = reinterpret_cast<const uint16_t*>(ws + WS_IDXF)[row];
    const int k = tag & 1023;
    const int b = row >> 10, hw = row & 1023;
    const float* xin = in + b*(DIM*HW) + hw;
    const float* e = emb + k*DIM;
    float acc[4] = {0.f, 0.f, 0.f, 0.f};
#pragma unroll
    for (int q = 0; q < 16; ++q) {
        const float4 v = *(const float4*)(e + 4*q);
        acc[q&3] = fmaf(v.x, xin[(4*q+0)*HW], acc[q&3]);
        acc[q&3] = fmaf(v.y, xin[(4*q+1)*HW], acc[q&3]);
        acc[q&3] = fmaf(v.z, xin[(4*q+2)*HW], acc[q&3]);
        acc[q&3] = fmaf(v.w, xin[(4*q+3)*HW], acc[q&3]);
    }
    const float dot  = (acc[0]+acc[1]) + (acc[2]+acc[3]);
    const float dist = fmaf(-2.f, dot, ws[WS_E2F + k]);
    const bool tbad = reinterpret_cast<const uint32_t*>(ws)[WS_TBAD] != 0u;
    const bool bad = tbad || (tag & 0x8000u) ||
                     (fabsf(dist - ws[WS_BD1 + row]) > TOLF);
    if (bad) {
        const uint32_t pos = atomicAdd(reinterpret_cast<uint32_t*>(ws) + WS_NFLAG, 1u);
        reinterpret_cast<uint16_t*>(ws + WS_FLGF)[pos] = (uint16_t)row;
    }
}

// ---------------- exact fp32 re-resolve for flagged rows (16 threads/row) ----------------
__global__ __launch_bounds__(256) void vq_exact(const float* __restrict__ in,
                                                const float* __restrict__ emb,
                                                float* __restrict__ ws) {
    const int gt = blockIdx.x*256 + threadIdx.x;
    const int slot = gt >> 4, sub = gt & 15;
    const int nslots = (gridDim.x * 256) >> 4;
    const uint32_t nf = reinterpret_cast<const uint32_t*>(ws)[WS_NFLAG];
    const float* e2f = ws + WS_E2F;
    const uint16_t* flg = reinterpret_cast<const uint16_t*>(ws + WS_FLGF);
    uint16_t* idx = reinterpret_cast<uint16_t*>(ws + WS_IDXF);
    for (uint32_t i = slot; i < nf; i += nslots) {
        const int row = flg[i];
        const int b = row >> 10, hw = row & 1023;
        const float* xin = in + b*(DIM*HW) + hw;
        float xv[64];
#pragma unroll
        for (int c = 0; c < 64; ++c) xv[c] = xin[c*HW];
        float best = 3.4e38f; int bk = 0;
        for (int kk = 0; kk < 64; ++kk) {
            const int k = sub*64 + kk;
            const float* e = emb + k*DIM;
            float acc[4] = {0.f, 0.f, 0.f, 0.f};
#pragma unroll
            for (int q = 0; q < 16; ++q) {
                const float4 v = *(const float4*)(e + 4*q);
                acc[q&3] = fmaf(v.x, xv[4*q+0], acc[q&3]);
                acc[q&3] = fmaf(v.y, xv[4*q+1], acc[q&3]);
                acc[q&3] = fmaf(v.z, xv[4*q+2], acc[q&3]);
                acc[q&3] = fmaf(v.w, xv[4*q+3], acc[q&3]);
            }
            const float dot = (acc[0]+acc[1]) + (acc[2]+acc[3]);
            const float dist = fmaf(-2.f, dot, e2f[k]);
            if (dist < best) { best = dist; bk = k; }
        }
#pragma unroll
        for (int off = 1; off < 16; off <<= 1) {
            const float od = __shfl_xor(best, off, 64);
            const int   ok = __shfl_xor(bk, off, 64);
            if (od < best || (od == best && ok < bk)) { best = od; bk = ok; }
        }
        if (sub == 0) idx[row] = (uint16_t)bk;
    }
}

// ---------------- epilogue: gather, STE write, loss, counts ----------------
__global__ __launch_bounds__(256) void vq_epilogue(const float* __restrict__ in,
                                                   const float* __restrict__ emb,
                                                   float* __restrict__ out,
                                                   float* __restrict__ ws) {
    const int t = threadIdx.x;
    const int row = blockIdx.x*64 + (t & 63);
    const int cg = t >> 6;
    const int b = row >> 10, hw = row & 1023;
    const int bestk = reinterpret_cast<const uint16_t*>(ws + WS_IDXF)[row] & 1023;
    if (cg == 0) atomicAdd(reinterpret_cast<uint32_t*>(ws) + WS_CNT + bestk, 1u);
    const float* xin  = in  + b*(DIM*HW) + hw;
    float*       outp = out + b*(DIM*HW) + hw;
    const float4* eq = reinterpret_cast<const float4*>(emb + bestk*DIM + 16*cg);
    float lsum = 0.f;
#pragma unroll
    for (int i2 = 0; i2 < 4; ++i2) {
        const float4 q = eq[i2];
        const int c0 = 16*cg + 4*i2;
        const float x0 = xin[(c0+0)*HW], x1 = xin[(c0+1)*HW];
        const float x2 = xin[(c0+2)*HW], x3 = xin[(c0+3)*HW];
        const float d0 = q.x-x0, d1 = q.y-x1, d2 = q.z-x2, d3 = q.w-x3;
        lsum += d0*d0 + d1*d1 + d2*d2 + d3*d3;
        outp[(c0+0)*HW] = x0+d0; outp[(c0+1)*HW] = x1+d1;
        outp[(c0+2)*HW] = x2+d2; outp[(c0+3)*HW] = x3+d3;
    }
#pragma unroll
    for (int off = 32; off; off >>= 1) lsum += __shfl_down(lsum, off, 64);
    __shared__ float lred[4];
    if ((t & 63) == 0) lred[t >> 6] = lsum;
    __syncthreads();
    if (t == 0) atomicAdd(ws + WS_LOSS, (lred[0]+lred[1]) + (lred[2]+lred[3]));
}

__global__ void vq_final(float* __restrict__ out, const float* __restrict__ ws) {
    __shared__ float red[16];
    const int t = threadIdx.x;  // 1024
    const uint32_t* counts = reinterpret_cast<const uint32_t*>(ws) + WS_CNT;
    float p = (float)counts[t] * (1.0f / 65536.f);
    float v = p * logf(p + 1e-10f);
#pragma unroll
    for (int off = 32; off; off >>= 1) v += __shfl_down(v, off, 64);
    if ((t & 63) == 0) red[t >> 6] = v;
    __syncthreads();
    if (t == 0) {
        float s = 0.f;
#pragma unroll
        for (int i = 0; i < 16; ++i) s += red[i];
        out[OUT_ELEMS]     = 0.25f * (1.0f / (float)OUT_ELEMS) * ws[WS_LOSS];
        out[OUT_ELEMS + 1] = expf(-s);
    }
}

// ---------------- fallback (ws too small): round-3 fused path ----------------
__global__ void vq_init(const float* __restrict__ emb, float* __restrict__ ws) {
    const int k = blockIdx.x * blockDim.x + threadIdx.x;
    if (k < K_CODES) {
        const float4* e4 = reinterpret_cast<const float4*>(emb + k * DIM);
        float s = 0.f;
#pragma unroll
        for (int i = 0; i < 16; ++i) {
            float4 v = e4[i];
            s += v.x*v.x + v.y*v.y + v.z*v.z + v.w*v.w;
        }
        ws[WS_E2F + k] = s;
        reinterpret_cast<uint32_t*>(ws)[WS_CNT + k] = 0u;
    }
    if (blockIdx.x == 0 && threadIdx.x == 0) ws[WS_LOSS] = 0.f;
}

__global__ __launch_bounds__(256, 4) void vq_fused(
    const float* __restrict__ in, const float* __restrict__ emb,
    float* __restrict__ out, float* __restrict__ ws)
{
    const int row = blockIdx.x * 256 + threadIdx.x;
    const int b = row >> 10, hw = row & 1023;
    const float* xin = in + b * (DIM*HW) + hw;
    float xv[64];
#pragma unroll
    for (int c = 0; c < 64; ++c) xv[c] = xin[c*HW];
    const float* e2 = ws + WS_E2F;
    float best = 3.4e38f; int bestk = 0;
    for (int k = 0; k < K_CODES; ++k) {
        const float* e = emb + k*DIM;
        float acc[4] = {0.f, 0.f, 0.f, 0.f};
#pragma unroll
        for (int i = 0; i < 16; ++i) {
            const float4 v = *(const float4*)(e + 4*i);
            acc[i&3] = fmaf(v.x, xv[4*i+0], acc[i&3]);
            acc[i&3] = fmaf(v.y, xv[4*i+1], acc[i&3]);
            acc[i&3] = fmaf(v.z, xv[4*i+2], acc[i&3]);
            acc[i&3] = fmaf(v.w, xv[4*i+3], acc[i&3]);
        }
        const float dot = (acc[0]+acc[1]) + (acc[2]+acc[3]);
        const float dist = fmaf(-2.f, dot, e2[k]);
        if (dist < best) { best = dist; bestk = k; }
    }
    atomicAdd(reinterpret_cast<uint32_t*>(ws) + WS_CNT + bestk, 1u);
    float* outp = out + b*(DIM*HW) + hw;
    const float4* eq = reinterpret_cast<const float4*>(emb + bestk*DIM);
    float lsum = 0.f;
#pragma unroll
    for (int i = 0; i < 16; ++i) {
        const float4 q = eq[i];
        const int c0 = 4*i;
        const float d0 = q.x-xv[c0+0], d1 = q.y-xv[c0+1];
        const float d2 = q.z-xv[c0+2], d3 = q.w-xv[c0+3];
        lsum += d0*d0 + d1*d1 + d2*d2 + d3*d3;
        outp[(c0+0)*HW] = xv[c0+0]+d0; outp[(c0+1)*HW] = xv[c0+1]+d1;
        outp[(c0+2)*HW] = xv[c0+2]+d2; outp[(c0+3)*HW] = xv[c0+3]+d3;
    }
#pragma unroll
    for (int off = 32; off; off >>= 1) lsum += __shfl_down(lsum, off, 64);
    __shared__ float lred[4];
    if ((threadIdx.x & 63) == 0) lred[threadIdx.x >> 6] = lsum;
    __syncthreads();
    if (threadIdx.x == 0) atomicAdd(ws + WS_LOSS, (lred[0]+lred[1])+(lred[2]+lred[3]));
}

extern "C" void kernel_launch(void* const* d_in, const int* in_sizes, int n_in,
                              void* d_out, int out_size, void* d_ws, size_t ws_size,
                              hipStream_t stream) {
    const float* in  = (const float*)d_in[0];
    const float* emb = (const float*)d_in[1];
    float* out = (float*)d_out;
    float* ws  = (float*)d_ws;

    if (ws_size >= (size_t)WS_NEED_FLOATS * 4) {
        vq_prep<<<4, 256, 0, stream>>>(emb, ws);
        vq_tabcheck<<<4, 256, 0, stream>>>(emb, ws);
        vq_mfma<<<1024, 256, 0, stream>>>(in, ws);
        vq_verify<<<256, 256, 0, stream>>>(in, emb, ws);
        vq_exact<<<512, 256, 0, stream>>>(in, emb, ws);
        vq_epilogue<<<1024, 256, 0, stream>>>(in, emb, out, ws);
        vq_final<<<1, 1024, 0, stream>>>(out, ws);
    } else {
        vq_init<<<4, 256, 0, stream>>>(emb, ws);
        vq_fused<<<N_ROWS / 256, 256, 0, stream>>>(in, emb, out, ws);
        vq_final<<<1, 1024, 0, stream>>>(out, ws);
    }
}

// Round 6
// 182.434 us; speedup vs baseline: 11.5143x; 11.5143x over previous
//
#include <hip/hip_runtime.h>
#include <stdint.h>

// VectorQuantizer (eval fwd): inputs [64,64,32,32] f32 NCHW, embedding [1024,64] f32.
// Outputs concatenated: quantized [64,64,32,32] f32, loss scalar, perplexity scalar.
//
// Pure fp32 path (bit-exact vs reference selections; passed rounds 2/3/5 absmax 0.0).
// distances = ||e_k||^2 - 2 x.e_k (row-constant ||x||^2 dropped).
// All lanes scan the SAME code k -> embedding loads wave-uniform -> s_load
// (scalar pipe) -> inner loop is pure v_fma (SGPR e, VGPR x).
//
// Round-6 fix: x pinned in VGPRs via a REAL no-op asm (v_mov_b32 %0,%0).
// Round 3 used an empty asm string, which LLVM treats as a no-op and the x
// loads sank into the k-loop (VGPR_Count=40, VALUBusy 46%). A real mov's
// output feeds the loop -> 64 values must stay register-resident.

#define K_CODES 1024
#define DIM 64
#define HW 1024          // 32*32
#define N_ROWS 65536
#define OUT_ELEMS 4194304

// ws layout (float indices)
#define WS_E2   0        // 1024 f32: ||e_k||^2
#define WS_CNT  1024     // 1024 u32: counts
#define WS_LOSS 2048     // 1 f32
#define WS_PD   4096     // SP*N_ROWS f32 partial dists; then SP*N_ROWS i32 partial ks

__global__ void vq_init(const float* __restrict__ emb, float* __restrict__ ws) {
    const int k = blockIdx.x * blockDim.x + threadIdx.x;  // 1024 threads total
    if (k < K_CODES) {
        const float4* e4 = reinterpret_cast<const float4*>(emb + k * DIM);
        float s = 0.f;
#pragma unroll
        for (int i = 0; i < DIM / 4; ++i) {
            float4 v = e4[i];
            s += v.x * v.x + v.y * v.y + v.z * v.z + v.w * v.w;
        }
        ws[WS_E2 + k] = s;
        reinterpret_cast<unsigned int*>(ws)[WS_CNT + k] = 0u;
    }
    if (blockIdx.x == 0 && threadIdx.x == 0) ws[WS_LOSS] = 0.f;
}

template <int SP>
__global__ __launch_bounds__(256, 2) void vq_argmin_g(
    const float* __restrict__ in, const float* __restrict__ emb,
    float* __restrict__ ws)
{
    const int blk   = blockIdx.x;
    const int split = blk & (SP - 1);
    const int row   = (blk / SP) * 256 + threadIdx.x;
    const int b     = row >> 10;
    const int hw    = row & 1023;

    const float* xin = in + b * (DIM * HW) + hw;
    float xv[DIM];
#pragma unroll
    for (int c = 0; c < DIM; ++c) xv[c] = xin[c * HW];
    // Pin x in VGPRs with a REAL instruction (empty asm is LLVM-no-op'd).
    // The mov's output is the only path to the value -> no re-load possible.
#pragma unroll
    for (int c = 0; c < DIM; ++c)
        asm volatile("v_mov_b32 %0, %0" : "+v"(xv[c]));

    const float* e2 = ws + WS_E2;
    float best  = 3.4e38f;
    int   bestk = 0;

    constexpr int KPER = K_CODES / SP;
    const int k0 = split * KPER;
    for (int kk = 0; kk < KPER; ++kk) {
        const int k = k0 + kk;
        const float* e = emb + k * DIM;       // wave-uniform -> s_load
        const float e2v = e2[k];
        float acc[4] = {0.f, 0.f, 0.f, 0.f};
#pragma unroll
        for (int i = 0; i < 16; ++i) {
            const float4 v = *reinterpret_cast<const float4*>(e + 4 * i);
            acc[i & 3] = fmaf(v.x, xv[4 * i + 0], acc[i & 3]);
            acc[i & 3] = fmaf(v.y, xv[4 * i + 1], acc[i & 3]);
            acc[i & 3] = fmaf(v.z, xv[4 * i + 2], acc[i & 3]);
            acc[i & 3] = fmaf(v.w, xv[4 * i + 3], acc[i & 3]);
        }
        const float dot  = (acc[0] + acc[1]) + (acc[2] + acc[3]);
        const float dist = fmaf(-2.f, dot, e2v);
        if (dist < best) { best = dist; bestk = k; }
    }

    ws[WS_PD + split * N_ROWS + row] = best;
    reinterpret_cast<int*>(ws)[WS_PD + SP * N_ROWS + split * N_ROWS + row] = bestk;
}

// 64 rows x 4 channel-groups per 256-thread block.
template <int SP>
__global__ __launch_bounds__(256, 4) void vq_epilogue(
    const float* __restrict__ in, const float* __restrict__ emb,
    float* __restrict__ out, float* __restrict__ ws)
{
    const int tid = threadIdx.x;
    const int row = blockIdx.x * 64 + (tid & 63);
    const int cg  = tid >> 6;          // 0..3 -> channels [16*cg, 16*cg+16)
    const int b   = row >> 10;
    const int hw  = row & 1023;

    const int* pk = reinterpret_cast<const int*>(ws) + WS_PD + SP * N_ROWS;
    float best  = ws[WS_PD + row];
    int   bestk = pk[row];
#pragma unroll
    for (int s = 1; s < SP; ++s) {
        const float d = ws[WS_PD + s * N_ROWS + row];
        const int   k = pk[s * N_ROWS + row];
        if (d < best || (d == best && k < bestk)) { best = d; bestk = k; }
    }

    if (cg == 0)
        atomicAdd(reinterpret_cast<unsigned int*>(ws) + WS_CNT + bestk, 1u);

    const float*  xin  = in  + b * (DIM * HW) + hw;
    float*        outp = out + b * (DIM * HW) + hw;
    const float4* eq   = reinterpret_cast<const float4*>(emb + bestk * DIM + 16 * cg);

    float lsum = 0.f;
#pragma unroll
    for (int i = 0; i < 4; ++i) {
        const float4 q = eq[i];
        const int c0 = 16 * cg + 4 * i;
        const float x0 = xin[(c0 + 0) * HW];
        const float x1 = xin[(c0 + 1) * HW];
        const float x2 = xin[(c0 + 2) * HW];
        const float x3 = xin[(c0 + 3) * HW];
        const float d0 = q.x - x0, d1 = q.y - x1, d2 = q.z - x2, d3 = q.w - x3;
        lsum += d0 * d0 + d1 * d1 + d2 * d2 + d3 * d3;
        outp[(c0 + 0) * HW] = x0 + d0;   // STE: x + (q - x)
        outp[(c0 + 1) * HW] = x1 + d1;
        outp[(c0 + 2) * HW] = x2 + d2;
        outp[(c0 + 3) * HW] = x3 + d3;
    }

#pragma unroll
    for (int off = 32; off; off >>= 1) lsum += __shfl_down(lsum, off, 64);
    __shared__ float lred[4];
    const int lane = tid & 63;
    const int wid  = tid >> 6;
    if (lane == 0) lred[wid] = lsum;
    __syncthreads();
    if (tid == 0)
        atomicAdd(ws + WS_LOSS, (lred[0] + lred[1]) + (lred[2] + lred[3]));
}

// Fallback if ws too small for partials: fully fused.
__global__ __launch_bounds__(256, 2) void vq_fused(
    const float* __restrict__ in, const float* __restrict__ emb,
    float* __restrict__ out, float* __restrict__ ws)
{
    const int row = blockIdx.x * 256 + threadIdx.x;
    const int b   = row >> 10;
    const int hw  = row & 1023;

    const float* xin = in + b * (DIM * HW) + hw;
    float xv[DIM];
#pragma unroll
    for (int c = 0; c < DIM; ++c) xv[c] = xin[c * HW];
#pragma unroll
    for (int c = 0; c < DIM; ++c)
        asm volatile("v_mov_b32 %0, %0" : "+v"(xv[c]));

    const float* e2 = ws + WS_E2;
    float best  = 3.4e38f;
    int   bestk = 0;
    for (int k = 0; k < K_CODES; ++k) {
        const float* e = emb + k * DIM;
        const float e2v = e2[k];
        float acc[4] = {0.f, 0.f, 0.f, 0.f};
#pragma unroll
        for (int i = 0; i < 16; ++i) {
            const float4 v = *reinterpret_cast<const float4*>(e + 4 * i);
            acc[i & 3] = fmaf(v.x, xv[4 * i + 0], acc[i & 3]);
            acc[i & 3] = fmaf(v.y, xv[4 * i + 1], acc[i & 3]);
            acc[i & 3] = fmaf(v.z, xv[4 * i + 2], acc[i & 3]);
            acc[i & 3] = fmaf(v.w, xv[4 * i + 3], acc[i & 3]);
        }
        const float dot  = (acc[0] + acc[1]) + (acc[2] + acc[3]);
        const float dist = fmaf(-2.f, dot, e2v);
        if (dist < best) { best = dist; bestk = k; }
    }

    atomicAdd(reinterpret_cast<unsigned int*>(ws) + WS_CNT + bestk, 1u);

    float*        outp = out + b * (DIM * HW) + hw;
    const float4* eq   = reinterpret_cast<const float4*>(emb + bestk * DIM);
    float lsum = 0.f;
#pragma unroll
    for (int i = 0; i < 16; ++i) {
        const float4 q = eq[i];
        const int c0 = 4 * i;
        const float d0 = q.x - xv[c0 + 0], d1 = q.y - xv[c0 + 1];
        const float d2 = q.z - xv[c0 + 2], d3 = q.w - xv[c0 + 3];
        lsum += d0 * d0 + d1 * d1 + d2 * d2 + d3 * d3;
        outp[(c0 + 0) * HW] = xv[c0 + 0] + d0;
        outp[(c0 + 1) * HW] = xv[c0 + 1] + d1;
        outp[(c0 + 2) * HW] = xv[c0 + 2] + d2;
        outp[(c0 + 3) * HW] = xv[c0 + 3] + d3;
    }
#pragma unroll
    for (int off = 32; off; off >>= 1) lsum += __shfl_down(lsum, off, 64);
    __shared__ float lred[4];
    if ((threadIdx.x & 63) == 0) lred[threadIdx.x >> 6] = lsum;
    __syncthreads();
    if (threadIdx.x == 0)
        atomicAdd(ws + WS_LOSS, (lred[0] + lred[1]) + (lred[2] + lred[3]));
}

__global__ void vq_final(float* __restrict__ out, const float* __restrict__ ws) {
    __shared__ float red[16];
    const int t = threadIdx.x;  // 1024 threads
    const unsigned int* counts = reinterpret_cast<const unsigned int*>(ws) + WS_CNT;
    float p = (float)counts[t] * (1.0f / 65536.f);
    float v = p * logf(p + 1e-10f);
#pragma unroll
    for (int off = 32; off; off >>= 1) v += __shfl_down(v, off, 64);
    if ((t & 63) == 0) red[t >> 6] = v;
    __syncthreads();
    if (t == 0) {
        float s = 0.f;
#pragma unroll
        for (int i = 0; i < 16; ++i) s += red[i];
        out[OUT_ELEMS]     = 0.25f * (1.0f / (float)OUT_ELEMS) * ws[WS_LOSS];
        out[OUT_ELEMS + 1] = expf(-s);
    }
}

extern "C" void kernel_launch(void* const* d_in, const int* in_sizes, int n_in,
                              void* d_out, int out_size, void* d_ws, size_t ws_size,
                              hipStream_t stream) {
    const float* in  = (const float*)d_in[0];
    const float* emb = (const float*)d_in[1];
    float* out = (float*)d_out;
    float* ws  = (float*)d_ws;

    const size_t need8 = (size_t)(WS_PD + 2 * 8 * N_ROWS) * 4;
    const size_t need4 = (size_t)(WS_PD + 2 * 4 * N_ROWS) * 4;

    vq_init<<<4, 256, 0, stream>>>(emb, ws);
    if (ws_size >= need8) {
        vq_argmin_g<8><<<(N_ROWS / 256) * 8, 256, 0, stream>>>(in, emb, ws);
        vq_epilogue<8><<<N_ROWS / 64, 256, 0, stream>>>(in, emb, out, ws);
    } else if (ws_size >= need4) {
        vq_argmin_g<4><<<(N_ROWS / 256) * 4, 256, 0, stream>>>(in, emb, ws);
        vq_epilogue<4><<<N_ROWS / 64, 256, 0, stream>>>(in, emb, out, ws);
    } else {
        vq_fused<<<N_ROWS / 256, 256, 0, stream>>>(in, emb, out, ws);
    }
    vq_final<<<1, 1024, 0, stream>>>(out, ws);
}